// Round 2
// baseline (901.653 us; speedup 1.0000x reference)
//
#include <hip/hip_runtime.h>
#include <hip/hip_bf16.h>

#define T_STEPS 2048
#define BATCH   256
#define DIM     128

// ---------------------------------------------------------------------------
// Kernel 1: Zx[t][b][g*4+k] = x[t,b,:] @ W_g[:128, k] + b_g[k] + theta_g[k]
// One thread per (t,b) row. W staged in LDS (broadcast reads).
// ---------------------------------------------------------------------------
__global__ __launch_bounds__(256) void zx_gemm(
    const float* __restrict__ x,
    const float* __restrict__ Wf, const float* __restrict__ bf, const float* __restrict__ thf,
    const float* __restrict__ Wi, const float* __restrict__ bi, const float* __restrict__ thi,
    const float* __restrict__ Wu, const float* __restrict__ bu, const float* __restrict__ thu,
    const float* __restrict__ Wo, const float* __restrict__ bo, const float* __restrict__ tho,
    float* __restrict__ Zx)
{
    __shared__ float lw[DIM * 16];
    __shared__ float bt[16];
    const int tid = threadIdx.x;

    for (int idx = tid; idx < DIM * 16; idx += 256) {
        int d = idx >> 4, u = idx & 15, g = u >> 2, k = u & 3;
        const float* W = (g == 0) ? Wf : (g == 1) ? Wi : (g == 2) ? Wu : Wo;
        lw[idx] = W[d * 4 + k];
    }
    if (tid < 16) {
        int g = tid >> 2, k = tid & 3;
        const float* bb = (g == 0) ? bf  : (g == 1) ? bi  : (g == 2) ? bu  : bo;
        const float* tt = (g == 0) ? thf : (g == 1) ? thi : (g == 2) ? thu : tho;
        bt[tid] = bb[k] + tt[k];
    }
    __syncthreads();

    size_t row = (size_t)blockIdx.x * 256 + tid;      // 0 .. T*B-1
    const float4* xr = (const float4*)(x + row * DIM);

    float acc[16];
#pragma unroll
    for (int u = 0; u < 16; ++u) acc[u] = bt[u];

#pragma unroll 4
    for (int d4 = 0; d4 < DIM / 4; ++d4) {
        float4 xv = xr[d4];
        const float* w = &lw[d4 * 64];
#pragma unroll
        for (int u = 0; u < 16; ++u) acc[u] = fmaf(xv.x, w[u],      acc[u]);
#pragma unroll
        for (int u = 0; u < 16; ++u) acc[u] = fmaf(xv.y, w[16 + u], acc[u]);
#pragma unroll
        for (int u = 0; u < 16; ++u) acc[u] = fmaf(xv.z, w[32 + u], acc[u]);
#pragma unroll
        for (int u = 0; u < 16; ++u) acc[u] = fmaf(xv.w, w[48 + u], acc[u]);
    }

    float4* zr = (float4*)(Zx + row * 16);
    zr[0] = make_float4(acc[0],  acc[1],  acc[2],  acc[3]);
    zr[1] = make_float4(acc[4],  acc[5],  acc[6],  acc[7]);
    zr[2] = make_float4(acc[8],  acc[9],  acc[10], acc[11]);
    zr[3] = make_float4(acc[12], acc[13], acc[14], acc[15]);
}

// ---------------------------------------------------------------------------
// Kernel 2: sequential recurrence. 16 lanes per batch element:
//   lane u = g*4+k, g in {forget,input,update,output}, k in {0..3}.
// Block = 64 threads = 1 wave = 4 batch elements. Grid = 64 blocks.
// Cross-lane exchange via ds_bpermute (addresses loop-invariant).
// ---------------------------------------------------------------------------
__device__ __forceinline__ float bperm(int addr, float v) {
    return __int_as_float(__builtin_amdgcn_ds_bpermute(addr, __float_as_int(v)));
}

__global__ __launch_bounds__(64) void qlstm_rec(
    const float* __restrict__ Zx,
    const float* __restrict__ Wf, const float* __restrict__ Wi,
    const float* __restrict__ Wu, const float* __restrict__ Wo,
    float* __restrict__ out)
{
    const int tid = threadIdx.x;        // 0..63 == lane id
    const int u   = tid & 15;
    const int g   = u >> 2;
    const int k   = u & 3;
    const int b   = blockIdx.x * 4 + (tid >> 4);

    // hidden-part weights: W_g[128+j][k], j=0..3
    const float* Wg = (g == 0) ? Wf : (g == 1) ? Wi : (g == 2) ? Wu : Wo;
    const float wh0 = Wg[(DIM + 0) * 4 + k];
    const float wh1 = Wg[(DIM + 1) * 4 + k];
    const float wh2 = Wg[(DIM + 2) * 4 + k];
    const float wh3 = Wg[(DIM + 3) * 4 + k];

    // unified activation: y = sigmoid(p) for gates f,i,o; y = tanh(p) for g.
    // sigma(x) = rcp(1 + 2^(-1.4427*x)); tanh(x) = 2*sigma(2x)-1
    const bool  isg = (g == 2);
    const float s1  = isg ? -2.885390082f : -1.442695041f;
    const float m2  = isg ? 2.f : 1.f;
    const float m3  = isg ? -1.f : 0.f;

    // ds_bpermute byte addresses (loop-invariant)
    const int base4  = (tid & ~3)  << 2;
    const int a0 = base4, a1 = base4 + 4, a2 = base4 + 8, a3 = base4 + 12;
    const int base16 = (tid & ~15) << 2;
    const int qf = base16 + (k << 2);
    const int qi = qf + 16, qu = qf + 32, qo = qf + 48;

    const float* zp = Zx + b * 16 + u;      // stride per step: B*16 = 4096 floats
    const bool do_store = (u < 4);          // lanes u<4 have k=u, store h
    float* op = out + b * 4 + k;

    float h = 0.f, c = 0.f;

    // prefetch pipeline, distance 4
    float zb0 = zp[0];
    float zb1 = zp[1 * 4096];
    float zb2 = zp[2 * 4096];
    float zb3 = zp[3 * 4096];

    for (int t = 0; t < T_STEPS; ++t) {
        int tn = t + 4; tn = (tn < T_STEPS) ? tn : (T_STEPS - 1);
        float znew = zp[(size_t)tn * 4096];

        // gather h_j (every lane in a group-of-4 holds h for k = lane&3)
        float h0 = bperm(a0, h), h1 = bperm(a1, h), h2 = bperm(a2, h), h3 = bperm(a3, h);
        float z = zb0;
        z = fmaf(h0, wh0, z);
        z = fmaf(h1, wh1, z);
        z = fmaf(h2, wh2, z);
        z = fmaf(h3, wh3, z);

        // cos(z) via v_cos (revolutions) with fract range reduction
        float cs = __builtin_amdgcn_cosf(__builtin_amdgcn_fractf(z * 0.15915494309f));

        // cumulative product over k within the gate's 4 lanes
        float c0 = bperm(a0, cs), c1 = bperm(a1, cs), c2 = bperm(a2, cs), c3 = bperm(a3, cs);
        float p = c0;
        p *= (k >= 1) ? c1 : 1.f;
        p *= (k >= 2) ? c2 : 1.f;
        p *= (k >= 3) ? c3 : 1.f;

        // activation (sigmoid or tanh, branch-free)
        float e = __builtin_amdgcn_exp2f(p * s1);
        float y = fmaf(__builtin_amdgcn_rcpf(1.f + e), m2, m3);

        // gather f, i, g, o for this k
        float fv = bperm(qf, y);
        float iv = bperm(qi, y);
        float gv = bperm(qu, y);
        float ov = bperm(qo, y);

        c = fmaf(fv, c, iv * gv);
        float e2 = __builtin_amdgcn_exp2f(c * -2.885390082f);
        float th = fmaf(2.f, __builtin_amdgcn_rcpf(1.f + e2), -1.f);
        h = ov * th;

        if (do_store) op[(size_t)t * (BATCH * 4)] = h;

        zb0 = zb1; zb1 = zb2; zb2 = zb3; zb3 = znew;
    }

    if (do_store) {
        out[(size_t)T_STEPS * BATCH * 4 + b * 4 + k]             = h;  // hx
        out[(size_t)T_STEPS * BATCH * 4 + BATCH * 4 + b * 4 + k] = c;  // cx
    }
}

extern "C" void kernel_launch(void* const* d_in, const int* in_sizes, int n_in,
                              void* d_out, int out_size, void* d_ws, size_t ws_size,
                              hipStream_t stream) {
    const float* x  = (const float*)d_in[0];
    const float* Wf = (const float*)d_in[1];
    const float* bf = (const float*)d_in[2];
    const float* tf = (const float*)d_in[3];
    const float* Wi = (const float*)d_in[4];
    const float* bi = (const float*)d_in[5];
    const float* ti = (const float*)d_in[6];
    const float* Wu = (const float*)d_in[7];
    const float* bu = (const float*)d_in[8];
    const float* tu = (const float*)d_in[9];
    const float* Wo = (const float*)d_in[10];
    const float* bo = (const float*)d_in[11];
    const float* to = (const float*)d_in[12];
    float* out = (float*)d_out;
    float* Zx  = (float*)d_ws;   // T*B*16 floats = 33.5 MB

    zx_gemm<<<(T_STEPS * BATCH) / 256, 256, 0, stream>>>(
        x, Wf, bf, tf, Wi, bi, ti, Wu, bu, tu, Wo, bo, to, Zx);

    qlstm_rec<<<BATCH / 4, 64, 0, stream>>>(Zx, Wf, Wi, Wu, Wo, out);
}